// Round 8
// baseline (110.220 us; speedup 1.0000x reference)
//
#include <hip/hip_runtime.h>
#include <hip/hip_bf16.h>

// SignedAttention: B=4,H=8,L=2048,D=64; N_PATCHES=128 (16 ch/patch); keys = patches p+1..p+9.
// Round 8: two-kernel pipeline.
//  K1 prepack: K -> bf16 rows padded to pitch 72 (Kp[bh][2048][72], == LDS image);
//              V -> bf16 full transpose (Vp[bh][64][2048]).
//  K2 attn: staging via __builtin_amdgcn_global_load_lds (16B/lane DMA, zero VALU);
//           compute path identical to verified R6/R7 (value-based masking only).
// d_ws layout: [Kp 9.44 MB][Vp 8.39 MB][slack] (ws ~268 MB per harness fill).

#define LSEQ   2048
#define CH     16
#define WIN    9
#define GRP    8

#define SK 72    // K row pitch (elems) — matches Kp global pitch
#define SV 280   // Vt row pitch: DMA fills cols 0..255, cols 256..279 zeroed
#define SA 168   // A row pitch
#define UNELEMS 21504   // A: 8*16*168 = 21504 elems (43008 B); K image 36864 B fits inside

typedef __attribute__((ext_vector_type(8))) short bf16x8;
typedef __attribute__((ext_vector_type(4))) float f32x4;

union BF8 { bf16x8 v; unsigned int u[4]; };

// bf16 pair pack, round-half-up: low16 = bf16(a), high16 = bf16(b).
__device__ __forceinline__ unsigned int bfpack(float a, float b) {
  unsigned int ua = (__float_as_uint(a) + 0x8000u) >> 16;
  unsigned int ub = (__float_as_uint(b) + 0x8000u) & 0xFFFF0000u;
  return ua | ub;
}

__device__ __forceinline__ bf16x8 pack8(float4 a, float4 b) {
  BF8 r;
  r.u[0] = bfpack(a.x, a.y);
  r.u[1] = bfpack(a.z, a.w);
  r.u[2] = bfpack(b.x, b.y);
  r.u[3] = bfpack(b.z, b.w);
  return r.v;
}

// async 16B-per-lane global->LDS DMA; lds base must be wave-uniform (dest = base + lane*16)
__device__ __forceinline__ void dma16(const void* g, void* l) {
  __builtin_amdgcn_global_load_lds(
      (const __attribute__((address_space(1))) unsigned int*)g,
      (__attribute__((address_space(3))) unsigned int*)l, 16, 0, 0);
}

// ================= Kernel 1: prepack K (pitch-72 bf16 rows) + V (bf16 transpose) ============
__global__ __launch_bounds__(256)
void prepack_kernel(const float* __restrict__ K, const float* __restrict__ V,
                    unsigned short* __restrict__ Kp, unsigned short* __restrict__ Vp) {
  int gidx = blockIdx.x * 256 + threadIdx.x;
  if (gidx < 589824) {                     // K role: 65536 rows x 9 uint4-groups
    int g   = gidx % 9;
    int row = gidx / 9;
    uint4 out;
    if (g < 8) {
      const float4* src = (const float4*)K + (size_t)row * 16 + 2 * g;
      float4 a = src[0], b = src[1];
      out = make_uint4(bfpack(a.x, a.y), bfpack(a.z, a.w),
                       bfpack(b.x, b.y), bfpack(b.z, b.w));
    } else {
      out = make_uint4(0, 0, 0, 0);        // pad cols 64..71
    }
    *(uint4*)(Kp + (size_t)row * SK + g * 8) = out;
  } else {                                 // V role: transpose, 32bh x 64d x 256 col-groups
    int vidx = gidx - 589824;
    int d  = vidx & 63;
    int cg = (vidx >> 6) & 255;
    int bh = vidx >> 14;
    const float* src = V + ((size_t)bh * LSEQ + cg * 8) * 64 + d;   // coalesced over d
    float v[8];
#pragma unroll
    for (int j = 0; j < 8; j++) v[j] = src[j * 64];
    uint4 out = make_uint4(bfpack(v[0], v[1]), bfpack(v[2], v[3]),
                           bfpack(v[4], v[5]), bfpack(v[6], v[7]));
    *(uint4*)(Vp + ((size_t)bh * 64 + d) * LSEQ + cg * 8) = out;
  }
}

// ================= Kernel 2: attention ============
__global__ __launch_bounds__(512, 4)
void signed_attn_kernel(const float* __restrict__ Q,
                        const float* __restrict__ LS,
                        const unsigned short* __restrict__ Kp,
                        const unsigned short* __restrict__ Vp,
                        float* __restrict__ O) {
  __shared__ __align__(16) unsigned short Vt[64 * SV];   // DMA image of Vp window
  __shared__ __align__(16) unsigned short Un[UNELEMS];   // K DMA image, then A staging

  const int g  = blockIdx.x & 15;
  const int bh = blockIdx.x >> 4;
  const int t  = threadIdx.x;
  const int p0 = g * GRP;

  const int w  = t >> 6;
  const int l  = t & 63;
  const int lr = l & 15;
  const int q4 = l >> 4;

  const int p   = p0 + w;                              // this wave's query patch
  const int npk = (127 - p) < WIN ? (127 - p) : WIN;   // valid key patches (0 only for p=127)
  const int c0  = (p0 + 1) * CH;                       // staged window start (rows/cols)

  // ---- K window DMA: 256 rows x 144 B = 36 chunks of 1 KB (contiguous in Kp) ----
  // Overflow rows (edge blocks / rows >= kb) read adjacent ws bytes: finite, value-masked.
  const unsigned short* Kw = Kp + ((size_t)bh * LSEQ + c0) * SK;
  for (int c = w; c < 36; c += 8)
    dma16((const char*)Kw + c * 1024 + l * 16, (char*)Un + c * 1024);

  // ---- V window DMA: 64 d-rows x 512 B, 32 active lanes each ----
  const unsigned short* Vw = Vp + (size_t)bh * 64 * LSEQ + c0;
  if (l < 32) {
    for (int d = w; d < 64; d += 8)
      dma16((const char*)(Vw + (size_t)d * LSEQ) + l * 16, (char*)Vt + d * (SV * 2));
  }
  // zero Vt cols 256..279 (not DMA'd; must be finite — multiplied only by A=0)
  for (int e = t; e < 64 * 12; e += 512) {
    int d = e / 12, cdw = e % 12;
    *(unsigned int*)((char*)Vt + d * (SV * 2) + 512 + cdw * 4) = 0u;
  }

  // ---- Q fragments straight from global fp32 (overlaps DMA) ----
  const float* Qg = Q + ((size_t)bh * LSEQ + (size_t)p * CH) * 64;
  bf16x8 qa[2];
#pragma unroll
  for (int s = 0; s < 2; s++) {
    const float* qp = Qg + lr * 64 + q4 * 8 + 32 * s;
    qa[s] = pack8(*(const float4*)qp, *(const float4*)(qp + 4));
  }

  const float scale = fminf(30.f, fmaxf(1.f, __expf(LS[0]))) * 0.125f;
  const int koff = w * CH;

  __syncthreads();   // barrier 1: DMA drained (vmcnt(0)) + zero-fill visible

  // ---- QK^T: 9 tiles from K LDS image (garbage rows value-masked downstream) ----
  f32x4 sacc[WIN];
#pragma unroll
  for (int tl = 0; tl < WIN; tl++) {
    f32x4 acc = {0.f, 0.f, 0.f, 0.f};
#pragma unroll
    for (int s = 0; s < 2; s++) {
      bf16x8 b = *(const bf16x8*)&Un[(koff + tl * 16 + lr) * SK + q4 * 8 + 32 * s];
      acc = __builtin_amdgcn_mfma_f32_16x16x32_bf16(qa[s], b, acc, 0, 0, 0);
    }
    sacc[tl] = acc;   // S[row=q4*4+r][col=tl*16+lr]
  }

  __syncthreads();   // barrier 2: all waves done with K image; Un becomes the A buffer

  // ---- store UNNORMALIZED e1 = exp(scale*s) as bf16 in A-layout; masked cols -> 0.
  //      (value-based masking only: MFMA k-layout is unverified; positional masks broke R5)
  unsigned short* Aw = Un + w * 16 * SA;
#pragma unroll
  for (int tl = 0; tl < WIN; tl++) {
    const bool val = tl < npk;
#pragma unroll
    for (int r = 0; r < 4; r++) {
      float e1 = __expf(scale * sacc[tl][r]);
      unsigned int u = (__float_as_uint(e1) + 0x8000u) >> 16;
      Aw[(q4 * 4 + r) * SA + tl * 16 + lr] = (unsigned short)(val ? u : 0u);
    }
  }
#pragma unroll
  for (int r = 0; r < 4; r++)   // zero-pad cols 144..159 (read by k-step 4)
    Aw[(q4 * 4 + r) * SA + 144 + lr] = 0;

  // ---- PV + row sums by MFMA: O1=E1*V, O2=E2*V, S1=E1*1, S2=E2*1 (all-ones B) ----
  BF8 bones;
#pragma unroll
  for (int j = 0; j < 4; j++) bones.u[j] = 0x3F803F80u;

  f32x4 o1[4] = {{0,0,0,0},{0,0,0,0},{0,0,0,0},{0,0,0,0}};
  f32x4 o2[4] = {{0,0,0,0},{0,0,0,0},{0,0,0,0},{0,0,0,0}};
  f32x4 s1 = {0,0,0,0}, s2 = {0,0,0,0};

#pragma unroll
  for (int s = 0; s < 5; s++) {
    BF8 a1, a2;
    a1.v = *(const bf16x8*)&Aw[lr * SA + s * 32 + q4 * 8];
#pragma unroll
    for (int j = 0; j < 4; j++) {
      unsigned int d    = a1.u[j];
      unsigned int lo16 = d << 16;
      unsigned int hi16 = d & 0xFFFF0000u;
      float lo = __uint_as_float(lo16);
      float hi = __uint_as_float(hi16);
      float rl = (lo16 == 0u) ? 0.f : __builtin_amdgcn_rcpf(lo);
      float rh = (hi16 == 0u) ? 0.f : __builtin_amdgcn_rcpf(hi);
      a2.u[j] = bfpack(rl, rh);
    }
    s1 = __builtin_amdgcn_mfma_f32_16x16x32_bf16(a1.v, bones.v, s1, 0, 0, 0);
    s2 = __builtin_amdgcn_mfma_f32_16x16x32_bf16(a2.v, bones.v, s2, 0, 0, 0);
#pragma unroll
    for (int n = 0; n < 4; n++) {
      bf16x8 b = *(const bf16x8*)&Vt[(n * 16 + lr) * SV + koff + s * 32 + q4 * 8];
      o1[n] = __builtin_amdgcn_mfma_f32_16x16x32_bf16(a1.v, b, o1[n], 0, 0, 0);
      o2[n] = __builtin_amdgcn_mfma_f32_16x16x32_bf16(a2.v, b, o2[n], 0, 0, 0);
    }
  }

  // ---- epilogue: O = O1*rcp(S1) - O2*rcp(S2); row sums lane-aligned with O ----
  float* Og = O + ((size_t)bh * LSEQ + (size_t)p * CH) * 64;
  const bool live = (npk > 0);   // patch 127: fully masked -> exact 0
#pragma unroll
  for (int r = 0; r < 4; r++) {
    float rp = __builtin_amdgcn_rcpf(s1[r]);
    float rn = __builtin_amdgcn_rcpf(s2[r]);
#pragma unroll
    for (int n = 0; n < 4; n++) {
      float o = o1[n][r] * rp - o2[n][r] * rn;
      Og[(q4 * 4 + r) * 64 + n * 16 + lr] = live ? o : 0.f;
    }
  }
}

extern "C" void kernel_launch(void* const* d_in, const int* in_sizes, int n_in,
                              void* d_out, int out_size, void* d_ws, size_t ws_size,
                              hipStream_t stream) {
  const float* Q  = (const float*)d_in[0];
  const float* K  = (const float*)d_in[1];
  const float* V  = (const float*)d_in[2];
  const float* LS = (const float*)d_in[3];
  float* O = (float*)d_out;

  unsigned short* Kp = (unsigned short*)d_ws;                       // 32*2048*72*2 = 9.44 MB
  unsigned short* Vp = Kp + (size_t)32 * LSEQ * SK;                 // 32*64*2048*2 = 8.39 MB

  // K-role: 589824 threads (2304 blocks); V-role: 524288 threads (2048 blocks)
  prepack_kernel<<<dim3(4352), dim3(256), 0, stream>>>(K, V, Kp, Vp);
  // 32 bh * 16 patch-groups = 512 blocks = exactly 2 per CU
  signed_attn_kernel<<<dim3(512), dim3(512), 0, stream>>>(Q, LS, Kp, Vp, O);
}